// Round 1
// baseline (139.366 us; speedup 1.0000x reference)
//
#include <hip/hip_runtime.h>
#include <hip/hip_bf16.h>

// Problem constants (AttentionalPlanarRemapping): N=32, C=64, H=W=128, E=512
#define NB   32
#define CC   64
#define HW   16384          // 128*128
#define EE   512
#define CC2  4096           // C*C

// ---------------------------------------------------------------------------
// Kernel 1: logits[n][j] = dot(atts[n,:], W[j,:]) + b[j]
// grid 512 blocks x 256 threads; thread handles one (n, j) pair.
// j = blockIdx.x*8 + (t&7), n = t>>3  -> writes of 8 consecutive j per n.
// W (8 MiB) is read exactly once across the grid.
// ---------------------------------------------------------------------------
__global__ __launch_bounds__(256) void logits_kernel(
    const float* __restrict__ atts, const float* __restrict__ W,
    const float* __restrict__ b, float* __restrict__ logits) {
    const int t  = threadIdx.x;
    const int j  = blockIdx.x * 8 + (t & 7);
    const int n  = t >> 3;
    const float* __restrict__ wrow = W + (size_t)j * EE;
    const float* __restrict__ arow = atts + (size_t)n * EE;
    float acc = 0.f;
    #pragma unroll 4
    for (int k = 0; k < EE; k += 4) {
        float4 w4 = *reinterpret_cast<const float4*>(wrow + k);
        float4 a4 = *reinterpret_cast<const float4*>(arow + k);
        acc = fmaf(w4.x, a4.x, acc);
        acc = fmaf(w4.y, a4.y, acc);
        acc = fmaf(w4.z, a4.z, acc);
        acc = fmaf(w4.w, a4.w, acc);
    }
    logits[(size_t)n * CC2 + j] = acc + b[j];
}

// ---------------------------------------------------------------------------
// Kernel 2: first softmax over the flattened 4096, then per-row (64) softmax.
// One block per n. Output stored TRANSPOSED: aT[n][d][c] = a[n][c][d], so the
// einsum kernel reads a linear 64-float run per d.
// ---------------------------------------------------------------------------
__global__ __launch_bounds__(256) void softmax_kernel(
    const float* __restrict__ logits, float* __restrict__ aT) {
    const int n = blockIdx.x;
    const int t = threadIdx.x;
    __shared__ float s[CC2];
    __shared__ float wmax[4];
    __shared__ float wsum[4];

    const float* __restrict__ L = logits + (size_t)n * CC2;

    // load + thread-local max
    float lmax = -1e30f;
    for (int i = t; i < CC2; i += 256) {
        float v = L[i];
        s[i] = v;
        lmax = fmaxf(lmax, v);
    }
    #pragma unroll
    for (int off = 32; off > 0; off >>= 1) lmax = fmaxf(lmax, __shfl_xor(lmax, off));
    if ((t & 63) == 0) wmax[t >> 6] = lmax;
    __syncthreads();
    const float bmax = fmaxf(fmaxf(wmax[0], wmax[1]), fmaxf(wmax[2], wmax[3]));

    // exp + thread-local sum (each thread touches only its own s[i] entries)
    float lsum = 0.f;
    for (int i = t; i < CC2; i += 256) {
        float e = __expf(s[i] - bmax);
        s[i] = e;
        lsum += e;
    }
    #pragma unroll
    for (int off = 32; off > 0; off >>= 1) lsum += __shfl_xor(lsum, off);
    if ((t & 63) == 0) wsum[t >> 6] = lsum;
    __syncthreads();
    const float inv = 1.f / (wsum[0] + wsum[1] + wsum[2] + wsum[3]);

    for (int i = t; i < CC2; i += 256) s[i] *= inv;
    __syncthreads();

    // second softmax: row c over d (values are first-softmax outputs)
    if (t < CC) {
        const int c = t;
        const float* __restrict__ row = s + c * CC;
        float mx = -1e30f;
        #pragma unroll
        for (int d = 0; d < CC; ++d) mx = fmaxf(mx, row[d]);
        float sum = 0.f;
        #pragma unroll
        for (int d = 0; d < CC; ++d) sum += __expf(row[d] - mx);
        const float isum = 1.f / sum;
        float* __restrict__ dst = aT + (size_t)n * CC2 + c;   // aT[n][d][c]
        #pragma unroll
        for (int d = 0; d < CC; ++d) dst[d * CC] = __expf(row[d] - mx) * isum;
    }
}

// ---------------------------------------------------------------------------
// Kernel 3: out[n,c,px] = sum_d a[n,c,d] * img[n,d,px]
// grid (32 px-tiles, 32 n) x 256 threads. Each thread owns 2 pixels (float2),
// accumulates all 64 c in registers (128 VGPR acc). aT[n] staged in LDS;
// A-reads are wave-uniform broadcasts. Image read once, out written once.
// ---------------------------------------------------------------------------
__global__ __launch_bounds__(256) void einsum_kernel(
    const float* __restrict__ img, const float* __restrict__ aT,
    float* __restrict__ out) {
    const int n  = blockIdx.y;
    const int t  = threadIdx.x;
    const int px0 = (blockIdx.x * 256 + t) * 2;

    __shared__ float sA[CC][CC];   // sA[d][c] = a[n][c][d]
    {
        const float4* __restrict__ src = reinterpret_cast<const float4*>(aT + (size_t)n * CC2);
        float4* __restrict__ dst = reinterpret_cast<float4*>(&sA[0][0]);
        #pragma unroll
        for (int i = 0; i < 4; ++i) dst[t + i * 256] = src[t + i * 256];
    }
    __syncthreads();

    float acc0[CC], acc1[CC];
    #pragma unroll
    for (int c = 0; c < CC; ++c) { acc0[c] = 0.f; acc1[c] = 0.f; }

    const float* __restrict__ ip = img + (size_t)n * CC * HW + px0;
    #pragma unroll 4
    for (int d = 0; d < CC; ++d) {
        const float2 v = *reinterpret_cast<const float2*>(ip + (size_t)d * HW);
        #pragma unroll
        for (int c = 0; c < CC; ++c) {
            const float a = sA[d][c];
            acc0[c] = fmaf(a, v.x, acc0[c]);
            acc1[c] = fmaf(a, v.y, acc1[c]);
        }
    }

    float* __restrict__ op = out + (size_t)n * CC * HW + px0;
    #pragma unroll
    for (int c = 0; c < CC; ++c) {
        float2 r;
        r.x = acc0[c];
        r.y = acc1[c];
        *reinterpret_cast<float2*>(op + (size_t)c * HW) = r;
    }
}

// ---------------------------------------------------------------------------
extern "C" void kernel_launch(void* const* d_in, const int* in_sizes, int n_in,
                              void* d_out, int out_size, void* d_ws, size_t ws_size,
                              hipStream_t stream) {
    const float* images = (const float*)d_in[0];   // [32,64,128,128]
    const float* atts   = (const float*)d_in[1];   // [32,512]
    const float* W      = (const float*)d_in[2];   // [4096,512]
    const float* b      = (const float*)d_in[3];   // [4096]
    float* out = (float*)d_out;                    // [32,64,128,128]

    // workspace: logits [32*4096] + aT [32*4096]  (1 MiB total)
    float* logits = (float*)d_ws;
    float* aT     = logits + NB * CC2;

    logits_kernel<<<CC2 / 8, 256, 0, stream>>>(atts, W, b, logits);
    softmax_kernel<<<NB, 256, 0, stream>>>(logits, aT);
    einsum_kernel<<<dim3(HW / 512, NB), 256, 0, stream>>>(images, aT, out);
}